// Round 1
// baseline (622.969 us; speedup 1.0000x reference)
//
#include <hip/hip_runtime.h>
#include <math.h>

#define N_PTS 50000
#define KNN_K 16

using bf16x8 = __attribute__((ext_vector_type(8))) __bf16;
using bf16x4 = __attribute__((ext_vector_type(4))) __bf16;
using f32x4  = __attribute__((ext_vector_type(4))) float;

// ---------------------------------------------------------------------------
// Kernel 1: per-point features, interleaved: pg[n][0:64]=p0, pg[n][64:128]=p1
// ---------------------------------------------------------------------------
__global__ __launch_bounds__(256) void k1_pfeat(
    const float* __restrict__ xyz, const float* __restrict__ W1,
    const float* __restrict__ b1,  const float* __restrict__ W2,
    const float* __restrict__ b2,  float* __restrict__ pg)
{
    int i = blockIdx.x * 256 + threadIdx.x;
    if (i >= N_PTS) return;
    float x = xyz[3*i+0], y = xyz[3*i+1], z = xyz[3*i+2];
    float v[64];
    #pragma unroll
    for (int c = 0; c < 64; ++c)
        v[c] = b1[c] + x*W1[c] + y*W1[64+c] + z*W1[128+c];
    #pragma unroll 8
    for (int c = 0; c < 64; ++c) pg[(size_t)i*128 + c] = v[c];
    for (int c = 0; c < 64; ++c) {
        float a = b2[c];
        #pragma unroll
        for (int k = 0; k < 64; ++k) a += v[k] * W2[k*64 + c];
        pg[(size_t)i*128 + 64 + c] = a;
    }
}

// ---------------------------------------------------------------------------
// Kernel 3: repack W3a/W3b into bf16 MFMA fragments (unchanged layout):
// wf[(t*4+s)*512 + lane*8 + j] = W[k=s*32+(lane>>4)*8+j][c=t*16+(lane&15)]
// Used as the *A* operand of the swapped matmuls (A-frag of W^T == B-frag of W).
// ---------------------------------------------------------------------------
__global__ __launch_bounds__(256) void k3_wfrag(
    const float* __restrict__ W3a, const float* __restrict__ W3b,
    __bf16* __restrict__ wfA, __bf16* __restrict__ wfB)
{
    int ci = blockIdx.x * 256 + threadIdx.x;   // 0..2047 chunk id
    if (ci >= 2048) return;
    int t = ci >> 8, s = (ci >> 6) & 3, l = ci & 63;
    int k0 = s*32 + (l >> 4)*8;
    int c  = t*16 + (l & 15);
    #pragma unroll
    for (int j = 0; j < 8; ++j) {
        wfA[ci*8 + j] = (__bf16)W3a[(k0 + j)*128 + c];
        wfB[ci*8 + j] = (__bf16)W3b[(k0 + j)*128 + c];
    }
}

// ---------------------------------------------------------------------------
// Kernel 4: fused edge MLP, SWAPPED-operand form.  One wave = one point n.
// We compute h^T = W3a^T @ feat^T and out^T = W3b^T @ h^T:
//   A-operand = weight fragment (same bytes as before, wf unchanged)
//   B-operand = feat / h fragment (same bytes as the old A fragment)
//   C/D: lane holds D[m=outcol=t*16+quad*4+i][n=edge=lrow]
// => LDS h write is 4 consecutive bf16 (b64), output store is float4.
// p_local is computed inline (k2 fused): gather p0[j] slice per lane,
// butterfly max over the 16 lanes of the quad group (shfl_xor d=1,2,4,8).
// ---------------------------------------------------------------------------
__global__ __launch_bounds__(512) void k4_mlp(
    const float* __restrict__ pg, const int* __restrict__ knn,
    const __bf16* __restrict__ wfA, const __bf16* __restrict__ wfB,
    const float* __restrict__ b3a, const float* __restrict__ b3b,
    float* __restrict__ out)
{
    // 16 rows x 136 bf16 stride per wave; per-wave private tile, no syncthreads.
    __shared__ __align__(16) __bf16 lds_h[8][16*136];

    const int tid  = threadIdx.x;
    const int wave = tid >> 6;
    const int lane = tid & 63;
    const int lrow = lane & 15;   // edge slot kk (the MFMA n-dim now)
    const int quad = lane >> 4;   // 0..3

    const int n = blockIdx.x * 8 + wave;          // exact: 6250*8 = 50000
    const int j = knn[n*KNN_K + lrow];            // this edge's neighbor

    const float* pj = pg + (size_t)j*128;
    const float* pn = pg + (size_t)n*128;

    // ---- build feat fragments (B-operand layout == old A layout) ----------
    bf16x8 afrag[4];
    // cols 0..63: p1[j] - p1[n]
    #pragma unroll
    for (int s = 0; s < 2; ++s) {
        int o = 64 + s*32 + quad*8;
        float4 a0 = *(const float4*)(pj + o);
        float4 a1 = *(const float4*)(pj + o + 4);
        float4 c0 = *(const float4*)(pn + o);
        float4 c1 = *(const float4*)(pn + o + 4);
        bf16x8 f;
        f[0] = (__bf16)(a0.x - c0.x); f[1] = (__bf16)(a0.y - c0.y);
        f[2] = (__bf16)(a0.z - c0.z); f[3] = (__bf16)(a0.w - c0.w);
        f[4] = (__bf16)(a1.x - c1.x); f[5] = (__bf16)(a1.y - c1.y);
        f[6] = (__bf16)(a1.z - c1.z); f[7] = (__bf16)(a1.w - c1.w);
        afrag[s] = f;
    }
    // cols 64..127: p_local = max_k p0[knn[k]] - p0[n]  (fused former k2)
    #pragma unroll
    for (int s = 0; s < 2; ++s) {
        int o = s*32 + quad*8;
        float4 g0 = *(const float4*)(pj + o);
        float4 g1 = *(const float4*)(pj + o + 4);
        float m[8] = {g0.x, g0.y, g0.z, g0.w, g1.x, g1.y, g1.z, g1.w};
        #pragma unroll
        for (int d = 1; d < 16; d <<= 1) {
            #pragma unroll
            for (int q = 0; q < 8; ++q)
                m[q] = fmaxf(m[q], __shfl_xor(m[q], d));
        }
        float4 c0 = *(const float4*)(pn + o);
        float4 c1 = *(const float4*)(pn + o + 4);
        bf16x8 f;
        f[0] = (__bf16)(m[0] - c0.x); f[1] = (__bf16)(m[1] - c0.y);
        f[2] = (__bf16)(m[2] - c0.z); f[3] = (__bf16)(m[3] - c0.w);
        f[4] = (__bf16)(m[4] - c1.x); f[5] = (__bf16)(m[5] - c1.y);
        f[6] = (__bf16)(m[6] - c1.z); f[7] = (__bf16)(m[7] - c1.w);
        afrag[2 + s] = f;
    }

    // ---- matmul1 (swapped): acc[t][i] = h[edge=lrow][outcol=t*16+quad*4+i] --
    f32x4 acc[8];
    #pragma unroll
    for (int t = 0; t < 8; ++t)
        acc[t] = *(const f32x4*)(b3a + t*16 + quad*4);
    #pragma unroll
    for (int s = 0; s < 4; ++s) {
        #pragma unroll
        for (int t = 0; t < 8; ++t) {
            bf16x8 w = *(const bf16x8*)(wfA + (((t*4 + s)*64 + lane) << 3));
            acc[t] = __builtin_amdgcn_mfma_f32_16x16x32_bf16(w, afrag[s], acc[t], 0, 0, 0);
        }
    }

    // ---- exact gelu, vectorized b64 LDS write (4 consecutive cols/lane) ----
    __bf16* hb = &lds_h[wave][0];
    #pragma unroll
    for (int t = 0; t < 8; ++t) {
        bf16x4 hv;
        #pragma unroll
        for (int i = 0; i < 4; ++i) {
            float x = acc[t][i];
            float g = 0.5f * x * (1.0f + erff(x * 0.7071067811865475f));
            hv[i] = (__bf16)g;
        }
        *(bf16x4*)(hb + lrow*136 + t*16 + quad*4) = hv;
    }

    // ---- matmul2 (swapped): out[edge=lrow][outcol=t*16+quad*4+i] -----------
    f32x4 acc2[8];
    #pragma unroll
    for (int t = 0; t < 8; ++t)
        acc2[t] = *(const f32x4*)(b3b + t*16 + quad*4);
    #pragma unroll
    for (int s = 0; s < 4; ++s) {
        bf16x8 hfrag = *(const bf16x8*)(hb + lrow*136 + s*32 + quad*8);
        #pragma unroll
        for (int t = 0; t < 8; ++t) {
            bf16x8 w = *(const bf16x8*)(wfB + (((t*4 + s)*64 + lane) << 3));
            acc2[t] = __builtin_amdgcn_mfma_f32_16x16x32_bf16(w, hfrag, acc2[t], 0, 0, 0);
        }
    }

    // ---- store: float4 per (t), fully vectorized ---------------------------
    float* orow = out + (size_t)n * (KNN_K * 128) + (size_t)lrow * 128;
    #pragma unroll
    for (int t = 0; t < 8; ++t)
        *(f32x4*)(orow + t*16 + quad*4) = acc2[t];
}

// ---------------------------------------------------------------------------
extern "C" void kernel_launch(void* const* d_in, const int* in_sizes, int n_in,
                              void* d_out, int out_size, void* d_ws, size_t ws_size,
                              hipStream_t stream)
{
    const float* xyz = (const float*)d_in[0];
    const int*   knn = (const int*)  d_in[1];
    const float* W1  = (const float*)d_in[2];
    const float* b1  = (const float*)d_in[3];
    const float* W2  = (const float*)d_in[4];
    const float* b2  = (const float*)d_in[5];
    const float* W3a = (const float*)d_in[6];
    const float* b3a = (const float*)d_in[7];
    const float* W3b = (const float*)d_in[8];
    const float* b3b = (const float*)d_in[9];
    float* out = (float*)d_out;

    // workspace layout (~25.7 MB)
    float*  pg  = (float*)d_ws;                         // [N][128] = p0|p1
    __bf16* wfA = (__bf16*)(pg + (size_t)N_PTS * 128);  // 128*128 bf16
    __bf16* wfB = wfA + 128 * 128;

    hipLaunchKernelGGL(k3_wfrag, dim3(8), dim3(256), 0, stream, W3a, W3b, wfA, wfB);
    hipLaunchKernelGGL(k1_pfeat, dim3((N_PTS + 255) / 256), dim3(256), 0, stream,
                       xyz, W1, b1, W2, b2, pg);
    hipLaunchKernelGGL(k4_mlp, dim3(N_PTS / 8), dim3(512), 0, stream,
                       pg, knn, wfA, wfB, b3a, b3b, out);
}

// Round 2
// 581.878 us; speedup vs baseline: 1.0706x; 1.0706x over previous
//
#include <hip/hip_runtime.h>
#include <math.h>

#define N_PTS 50000
#define KNN_K 16

using bf16x8 = __attribute__((ext_vector_type(8))) __bf16;
using bf16x4 = __attribute__((ext_vector_type(4))) __bf16;
using f32x4  = __attribute__((ext_vector_type(4))) float;

// ---------------------------------------------------------------------------
// Kernel 1: per-point features, interleaved: pg[n][0:64]=p0, pg[n][64:128]=p1
// ---------------------------------------------------------------------------
__global__ __launch_bounds__(256) void k1_pfeat(
    const float* __restrict__ xyz, const float* __restrict__ W1,
    const float* __restrict__ b1,  const float* __restrict__ W2,
    const float* __restrict__ b2,  float* __restrict__ pg)
{
    int i = blockIdx.x * 256 + threadIdx.x;
    if (i >= N_PTS) return;
    float x = xyz[3*i+0], y = xyz[3*i+1], z = xyz[3*i+2];
    float v[64];
    #pragma unroll
    for (int c = 0; c < 64; ++c)
        v[c] = b1[c] + x*W1[c] + y*W1[64+c] + z*W1[128+c];
    #pragma unroll 8
    for (int c = 0; c < 64; ++c) pg[(size_t)i*128 + c] = v[c];
    for (int c = 0; c < 64; ++c) {
        float a = b2[c];
        #pragma unroll
        for (int k = 0; k < 64; ++k) a += v[k] * W2[k*64 + c];
        pg[(size_t)i*128 + 64 + c] = a;
    }
}

// ---------------------------------------------------------------------------
// Kernel 3: repack W3a/W3b into bf16 MFMA fragments (unchanged layout):
// wf[(t*4+s)*512 + lane*8 + j] = W[k=s*32+(lane>>4)*8+j][c=t*16+(lane&15)]
// wfA and wfB are ADJACENT in the workspace so k4 can stage both with one
// linear 64 KB copy into LDS.
// ---------------------------------------------------------------------------
__global__ __launch_bounds__(256) void k3_wfrag(
    const float* __restrict__ W3a, const float* __restrict__ W3b,
    __bf16* __restrict__ wfA, __bf16* __restrict__ wfB)
{
    int ci = blockIdx.x * 256 + threadIdx.x;   // 0..2047 chunk id
    if (ci >= 2048) return;
    int t = ci >> 8, s = (ci >> 6) & 3, l = ci & 63;
    int k0 = s*32 + (l >> 4)*8;
    int c  = t*16 + (l & 15);
    #pragma unroll
    for (int j = 0; j < 8; ++j) {
        wfA[ci*8 + j] = (__bf16)W3a[(k0 + j)*128 + c];
        wfB[ci*8 + j] = (__bf16)W3b[(k0 + j)*128 + c];
    }
}

// ---------------------------------------------------------------------------
// Kernel 4: fused edge MLP, swapped-operand MFMA form.  One wave = one point.
// NEW this round: block = 1024 threads (16 waves); wfA+wfB (64 KB) staged
// into LDS once per block -> weight fragment reads become conflict-free
// ds_read_b128 instead of per-wave 64 KB L1-thrashing global reloads.
// LDS: 64 KB weights + 16 x 4352 B h-tiles = 132 KB -> 1 block/CU,
// 4 waves/SIMD (launch_bounds caps VGPR at 128).
// ---------------------------------------------------------------------------
__global__ __launch_bounds__(1024, 4) void k4_mlp(
    const float* __restrict__ pg, const int* __restrict__ knn,
    const __bf16* __restrict__ wf,   // wfA (32 KB) followed by wfB (32 KB)
    const float* __restrict__ b3a, const float* __restrict__ b3b,
    float* __restrict__ out)
{
    __shared__ __align__(16) __bf16 lds_w[2*16384];     // 64 KB: wfA | wfB
    __shared__ __align__(16) __bf16 lds_h[16][16*136];  // 69.6 KB

    const int tid  = threadIdx.x;
    const int wave = tid >> 6;
    const int lane = tid & 63;
    const int lrow = lane & 15;   // edge slot kk (the MFMA n-dim)
    const int quad = lane >> 4;   // 0..3

    // ---- stage weights (one linear 64 KB copy, 16 B per thread x 4) -------
    {
        const f32x4* src = (const f32x4*)wf;
        f32x4* dst = (f32x4*)lds_w;
        #pragma unroll
        for (int u = 0; u < 4; ++u)
            dst[tid + u*1024] = src[tid + u*1024];
    }
    __syncthreads();

    const int n = blockIdx.x * 16 + wave;         // exact: 3125*16 = 50000
    const int j = knn[n*KNN_K + lrow];            // this edge's neighbor

    const float* pj = pg + (size_t)j*128;
    const float* pn = pg + (size_t)n*128;

    // ---- build feat fragments (B-operand layout) ---------------------------
    bf16x8 afrag[4];
    // cols 0..63: p1[j] - p1[n]
    #pragma unroll
    for (int s = 0; s < 2; ++s) {
        int o = 64 + s*32 + quad*8;
        float4 a0 = *(const float4*)(pj + o);
        float4 a1 = *(const float4*)(pj + o + 4);
        float4 c0 = *(const float4*)(pn + o);
        float4 c1 = *(const float4*)(pn + o + 4);
        bf16x8 f;
        f[0] = (__bf16)(a0.x - c0.x); f[1] = (__bf16)(a0.y - c0.y);
        f[2] = (__bf16)(a0.z - c0.z); f[3] = (__bf16)(a0.w - c0.w);
        f[4] = (__bf16)(a1.x - c1.x); f[5] = (__bf16)(a1.y - c1.y);
        f[6] = (__bf16)(a1.z - c1.z); f[7] = (__bf16)(a1.w - c1.w);
        afrag[s] = f;
    }
    // cols 64..127: p_local = max_k p0[knn[k]] - p0[n]  (fused former k2)
    #pragma unroll
    for (int s = 0; s < 2; ++s) {
        int o = s*32 + quad*8;
        float4 g0 = *(const float4*)(pj + o);
        float4 g1 = *(const float4*)(pj + o + 4);
        float m[8] = {g0.x, g0.y, g0.z, g0.w, g1.x, g1.y, g1.z, g1.w};
        #pragma unroll
        for (int d = 1; d < 16; d <<= 1) {
            #pragma unroll
            for (int q = 0; q < 8; ++q)
                m[q] = fmaxf(m[q], __shfl_xor(m[q], d));
        }
        float4 c0 = *(const float4*)(pn + o);
        float4 c1 = *(const float4*)(pn + o + 4);
        bf16x8 f;
        f[0] = (__bf16)(m[0] - c0.x); f[1] = (__bf16)(m[1] - c0.y);
        f[2] = (__bf16)(m[2] - c0.z); f[3] = (__bf16)(m[3] - c0.w);
        f[4] = (__bf16)(m[4] - c1.x); f[5] = (__bf16)(m[5] - c1.y);
        f[6] = (__bf16)(m[6] - c1.z); f[7] = (__bf16)(m[7] - c1.w);
        afrag[2 + s] = f;
    }

    // ---- matmul1 (swapped): acc[t][i] = h[edge=lrow][outcol=t*16+quad*4+i] --
    f32x4 acc[8];
    #pragma unroll
    for (int t = 0; t < 8; ++t)
        acc[t] = *(const f32x4*)(b3a + t*16 + quad*4);
    #pragma unroll
    for (int s = 0; s < 4; ++s) {
        #pragma unroll
        for (int t = 0; t < 8; ++t) {
            bf16x8 w = *(const bf16x8*)(lds_w + (((t*4 + s)*64 + lane) << 3));
            acc[t] = __builtin_amdgcn_mfma_f32_16x16x32_bf16(w, afrag[s], acc[t], 0, 0, 0);
        }
    }

    // ---- exact gelu, vectorized b64 LDS write (4 consecutive cols/lane) ----
    __bf16* hb = &lds_h[wave][0];
    #pragma unroll
    for (int t = 0; t < 8; ++t) {
        bf16x4 hv;
        #pragma unroll
        for (int i = 0; i < 4; ++i) {
            float x = acc[t][i];
            float g = 0.5f * x * (1.0f + erff(x * 0.7071067811865475f));
            hv[i] = (__bf16)g;
        }
        *(bf16x4*)(hb + lrow*136 + t*16 + quad*4) = hv;
    }

    // ---- matmul2 (swapped): out[edge=lrow][outcol=t*16+quad*4+i] -----------
    f32x4 acc2[8];
    #pragma unroll
    for (int t = 0; t < 8; ++t)
        acc2[t] = *(const f32x4*)(b3b + t*16 + quad*4);
    #pragma unroll
    for (int s = 0; s < 4; ++s) {
        bf16x8 hfrag = *(const bf16x8*)(hb + lrow*136 + s*32 + quad*8);
        #pragma unroll
        for (int t = 0; t < 8; ++t) {
            bf16x8 w = *(const bf16x8*)(lds_w + 16384 + (((t*4 + s)*64 + lane) << 3));
            acc2[t] = __builtin_amdgcn_mfma_f32_16x16x32_bf16(w, hfrag, acc2[t], 0, 0, 0);
        }
    }

    // ---- store: float4 per (t), fully vectorized ---------------------------
    float* orow = out + (size_t)n * (KNN_K * 128) + (size_t)lrow * 128;
    #pragma unroll
    for (int t = 0; t < 8; ++t)
        *(f32x4*)(orow + t*16 + quad*4) = acc2[t];
}

// ---------------------------------------------------------------------------
extern "C" void kernel_launch(void* const* d_in, const int* in_sizes, int n_in,
                              void* d_out, int out_size, void* d_ws, size_t ws_size,
                              hipStream_t stream)
{
    const float* xyz = (const float*)d_in[0];
    const int*   knn = (const int*)  d_in[1];
    const float* W1  = (const float*)d_in[2];
    const float* b1  = (const float*)d_in[3];
    const float* W2  = (const float*)d_in[4];
    const float* b2  = (const float*)d_in[5];
    const float* W3a = (const float*)d_in[6];
    const float* b3a = (const float*)d_in[7];
    const float* W3b = (const float*)d_in[8];
    const float* b3b = (const float*)d_in[9];
    float* out = (float*)d_out;

    // workspace layout (~25.7 MB)
    float*  pg  = (float*)d_ws;                         // [N][128] = p0|p1
    __bf16* wfA = (__bf16*)(pg + (size_t)N_PTS * 128);  // 128*128 bf16
    __bf16* wfB = wfA + 128 * 128;                      // adjacent to wfA

    hipLaunchKernelGGL(k3_wfrag, dim3(8), dim3(256), 0, stream, W3a, W3b, wfA, wfB);
    hipLaunchKernelGGL(k1_pfeat, dim3((N_PTS + 255) / 256), dim3(256), 0, stream,
                       xyz, W1, b1, W2, b2, pg);
    hipLaunchKernelGGL(k4_mlp, dim3(N_PTS / 16), dim3(1024), 0, stream,
                       pg, knn, wfA, b3a, b3b, out);
}